// Round 2
// baseline (4807.350 us; speedup 1.0000x reference)
//
#include <hip/hip_runtime.h>
#include <math.h>
#include <float.h>

#define B_ 8
#define N_ 4096
#define M_ (B_*N_)
#define KNN 10

__device__ __forceinline__ float mishf(float x){
  float sp = (x > 20.f) ? x : __logf(1.f + __expf(x));
  float e2 = __expf(-2.f*sp);
  float th = (1.f - e2) / (1.f + e2);
  return x * th;
}

// ---------------- transpose x (B,3,N) -> xp (B*N,3) ----------------
__global__ __launch_bounds__(256) void k_transpose_x(const float* __restrict__ x,
                                                     float* __restrict__ xp){
  int n = blockIdx.x*256 + threadIdx.x;
  if (n >= M_) return;
  int b = n >> 12, i = n & (N_-1);
  const float* xb = x + (size_t)b*3*N_;
  float v0 = xb[i], v1 = xb[N_+i], v2 = xb[2*N_+i];
  float* o = xp + (size_t)n*3;
  o[0]=v0; o[1]=v1; o[2]=v2;
}

// ---------------- xx[n] = sum_c X[n,c]^2 ----------------
template<int C>
__global__ __launch_bounds__(256) void k_xx(const float* __restrict__ X,
                                            float* __restrict__ xx){
  int n = blockIdx.x*256 + threadIdx.x;
  if (n >= M_) return;
  const float* r = X + (size_t)n*C;
  float s = 0.f;
#pragma unroll
  for (int c=0;c<C;c++){ float v=r[c]; s = fmaf(v,v,s); }
  xx[n] = s;
}

// ---------------- fused gram + top-10 kNN (register top-k) ----------------
// block: 64 rows x all 4096 cols, one batch. threads 16x16, thread tile 4x16.
// selection value: acc - 0.5*xx_j  (ordering identical to 2*acc - xx_i - xx_j)
template<int C>
__global__ __launch_bounds__(256,1) void k_knn(const float* __restrict__ X,
                                               const float* __restrict__ xx,
                                               int* __restrict__ idxout){
  constexpr int CP = (C+3)&~3;     // channels padded to 4
  constexpr int LS = CP + 4;       // LDS row stride (272B for C=64: 16B aligned)
  constexpr int JT = 256;          // j-tile cols
  constexpr int NIT = N_/JT;       // 16
  constexpr int XIF = 64*LS;
  constexpr int XJF = JT*LS;
  constexpr int MERGEF = 2*KNN*1024;                 // mv + mi, floats
  constexpr int SMEMF = (XIF+XJF) > MERGEF ? (XIF+XJF) : MERGEF;
  __shared__ float smem[SMEMF];
  __shared__ float hxxJ[JT];
  float* XI = smem;
  float* XJ = smem + XIF;

  const int t  = threadIdx.x;
  const int b  = blockIdx.y;
  const int i0 = blockIdx.x*64;
  const int tc = t & 15, tr = t >> 4;
  const float* Xb  = X  + (size_t)b*N_*C;
  const float* xxb = xx + (size_t)b*N_;

  // stage XI: 64 rows x CP
#pragma unroll
  for (int f = t; f < 64*(CP/4); f += 256){
    int r = f >> 4;            // CP/4 == 16 for C=64; for C=3, CP/4==1 handled below
    int c4 = f & ((CP/4)-1);
    if constexpr (CP/4 == 1) { r = f; c4 = 0; }
    float4 v;
    if constexpr (C % 4 == 0) v = *(const float4*)&Xb[(size_t)(i0+r)*C + c4*4];
    else { const float* p = &Xb[(size_t)(i0+r)*C]; v = make_float4(p[0],p[1],p[2],0.f); }
    *(float4*)&XI[r*LS + c4*4] = v;
  }

  float bv[4][KNN]; int bj[4][KNN];
#pragma unroll
  for (int rr=0;rr<4;rr++)
#pragma unroll
    for (int q=0;q<KNN;q++){ bv[rr][q] = -INFINITY; bj[rr][q] = 0x7fffffff; }

  for (int jt = 0; jt < NIT; ++jt){
    const int j0 = jt*JT;
    // stage XJ: 256 rows x CP, coalesced float4
#pragma unroll
    for (int f = t; f < JT*(CP/4); f += 256){
      int r = f >> 4;
      int c4 = f & ((CP/4)-1);
      if constexpr (CP/4 == 1) { r = f; c4 = 0; }
      float4 v;
      if constexpr (C % 4 == 0) v = *(const float4*)&Xb[(size_t)(j0+r)*C + c4*4];
      else { const float* p = &Xb[(size_t)(j0+r)*C]; v = make_float4(p[0],p[1],p[2],0.f); }
      *(float4*)&XJ[r*LS + c4*4] = v;
    }
    hxxJ[t] = 0.5f*xxb[j0+t];
    __syncthreads();

    float acc[4][16];
#pragma unroll
    for (int rr=0;rr<4;rr++)
#pragma unroll
      for (int s=0;s<16;s++) acc[rr][s]=0.f;

#pragma unroll 2
    for (int c4 = 0; c4 < CP/4; ++c4){
      float4 xi[4];
#pragma unroll
      for (int rr=0;rr<4;rr++) xi[rr] = *(const float4*)&XI[(tr*4+rr)*LS + c4*4];
#pragma unroll
      for (int s=0;s<16;s++){
        float4 xj = *(const float4*)&XJ[(tc + 16*s)*LS + c4*4];
#pragma unroll
        for (int rr=0;rr<4;rr++){
          float a0 = acc[rr][s];
          a0 = fmaf(xi[rr].x, xj.x, a0);
          a0 = fmaf(xi[rr].y, xj.y, a0);
          a0 = fmaf(xi[rr].z, xj.z, a0);
          a0 = fmaf(xi[rr].w, xj.w, a0);
          acc[rr][s] = a0;
        }
      }
    }

    // selection: 16 candidates per row, in-register top-k
#pragma unroll
    for (int s=0;s<16;s++){
      const int j = j0 + tc + 16*s;
      const float hx = hxxJ[tc + 16*s];
#pragma unroll
      for (int rr=0;rr<4;rr++){
        float v = acc[rr][s] - hx;
        if (v > bv[rr][KNN-1] || (v == bv[rr][KNN-1] && j < bj[rr][KNN-1])){
          float cv = v; int cj = j;
#pragma unroll
          for (int q=0;q<KNN;q++){
            bool better = (cv > bv[rr][q]) || (cv == bv[rr][q] && cj < bj[rr][q]);
            if (better){ float tv=bv[rr][q]; int tj=bj[rr][q]; bv[rr][q]=cv; bj[rr][q]=cj; cv=tv; cj=tj; }
          }
        }
      }
    }
    __syncthreads();   // XJ consumed; safe to restage
  }

  // dump per-thread lists to LDS: layout [slot][list=tc][row], stride-1 reads in merge
  float* mv = smem;
  int*   mi = (int*)(smem + KNN*1024);
#pragma unroll
  for (int rr=0;rr<4;rr++){
    const int r = tr*4 + rr;
#pragma unroll
    for (int q=0;q<KNN;q++){
      mv[q*1024 + tc*64 + r] = bv[rr][q];
      mi[q*1024 + tc*64 + r] = bj[rr][q];
    }
  }
  __syncthreads();

  if (t < 64){
    unsigned long long P = 0;   // 16 x 4-bit list pointers (max 10 < 16)
    int* o = idxout + ((size_t)b*N_ + i0 + t)*KNN;
    for (int slot=0; slot<KNN; ++slot){
      float best = -INFINITY; int bidx = 0x7fffffff; int bl = 0;
#pragma unroll
      for (int l=0;l<16;l++){
        const int pl = (int)((P >> (4*l)) & 15ull);
        const float v = mv[pl*1024 + l*64 + t];
        const int  jj = mi[pl*1024 + l*64 + t];
        if (v > best || (v == best && jj < bidx)){ best=v; bidx=jj; bl=l; }
      }
      P += 1ull << (4*bl);
      o[slot] = bidx;
    }
  }
}

// ---------------- generic GEMM: Y(M x Pfull) = act(s*(X1@Wa + X2@Wb)+b) ----------
// weight row for output col p: W + (p&hmask)*wstride + (p>>hshift)*hoff, length C
template<int PT>
__global__ __launch_bounds__(256) void k_gemm(
    const float* __restrict__ X1, int C1,
    const float* __restrict__ X2, int C2,
    const float* __restrict__ W, int hmask, int hshift, int wstride, int hoff,
    const float* __restrict__ g, const float* __restrict__ bb, int act,
    float* __restrict__ Y, int Pfull)
{
  constexpr int CPT = PT/16;     // cols per thread
  constexpr int WLS = PT + 4;
  __shared__ float Xt[32*68];    // [kk][r]
  __shared__ float Wt[32*WLS];   // [kk][p]
  const int t  = threadIdx.x;
  const int r0 = blockIdx.x*64;
  const int p0 = blockIdx.y*PT;
  const int cg = t & 15, rg = t >> 4;   // cols cg*CPT.., rows rg*4..
  const int C = C1 + C2;
  const int nkt = (C + 31) >> 5;

  float acc[4][CPT];
#pragma unroll
  for (int a=0;a<4;a++)
#pragma unroll
    for (int c=0;c<CPT;c++) acc[a][c]=0.f;

  for (int kt = 0; kt < nkt; ++kt){
    const int k0 = kt*32;
#pragma unroll
    for (int e = t; e < 64*32; e += 256){
      int kk = e & 31, r = e >> 5;
      int gk = k0 + kk;
      float v = 0.f;
      if (gk < C1) v = X1[(size_t)(r0+r)*C1 + gk];
      else if (gk < C) v = X2[(size_t)(r0+r)*C2 + (gk - C1)];
      Xt[kk*68 + r] = v;
    }
#pragma unroll
    for (int e = t; e < PT*32; e += 256){
      int kk = e & 31, p = e >> 5;
      int gp = p0 + p;
      int wrow = (gp & hmask)*wstride + (gp >> hshift)*hoff;
      int gk = k0 + kk;
      Wt[kk*WLS + p] = (gk < C) ? W[(size_t)wrow + gk] : 0.f;
    }
    __syncthreads();
#pragma unroll
    for (int kk=0;kk<32;kk++){
      float4 xv = *(const float4*)&Xt[kk*68 + rg*4];
      float xr[4] = {xv.x, xv.y, xv.z, xv.w};
      float wv[CPT];
#pragma unroll
      for (int c4=0;c4<CPT/4;c4++){
        float4 w4 = *(const float4*)&Wt[kk*WLS + cg*CPT + c4*4];
        wv[c4*4+0]=w4.x; wv[c4*4+1]=w4.y; wv[c4*4+2]=w4.z; wv[c4*4+3]=w4.w;
      }
#pragma unroll
      for (int rr=0;rr<4;rr++)
#pragma unroll
        for (int cc=0;cc<CPT;cc++)
          acc[rr][cc] = fmaf(xr[rr], wv[cc], acc[rr][cc]);
    }
    __syncthreads();
  }

  const float srs = rsqrtf(1.f + 1e-5f);
  float sv[CPT], bvv[CPT];
#pragma unroll
  for (int cc=0;cc<CPT;cc++){
    int gp = p0 + cg*CPT + cc;
    if (g){ sv[cc] = g[gp]*srs; bvv[cc] = bb[gp]; } else { sv[cc]=1.f; bvv[cc]=0.f; }
  }
#pragma unroll
  for (int rr=0;rr<4;rr++){
    size_t row = r0 + rg*4 + rr;
    float* yr = Y + row*(size_t)Pfull + p0 + cg*CPT;
#pragma unroll
    for (int c4=0;c4<CPT/4;c4++){
      float y0 = sv[c4*4+0]*acc[rr][c4*4+0] + bvv[c4*4+0];
      float y1 = sv[c4*4+1]*acc[rr][c4*4+1] + bvv[c4*4+1];
      float y2 = sv[c4*4+2]*acc[rr][c4*4+2] + bvv[c4*4+2];
      float y3 = sv[c4*4+3]*acc[rr][c4*4+3] + bvv[c4*4+3];
      if (act){ y0=mishf(y0); y1=mishf(y1); y2=mishf(y2); y3=mishf(y3); }
      *(float4*)&yr[c4*4] = make_float4(y0,y1,y2,y3);
    }
  }
}

// ---------------- edge gather + BN + mish + max over k ----------------
// ua layout: row m -> [u_0..u_{O-1}, a_0..a_{O-1}]
template<int O>
__global__ __launch_bounds__(256) void k_edgemax(
    const float* __restrict__ ua, const int* __restrict__ idx,
    const float* __restrict__ g, const float* __restrict__ bb,
    float* __restrict__ Y)
{
  constexpr int TPR = O/4;
  const int gt = blockIdx.x*256 + threadIdx.x;
  const int m  = gt / TPR;
  const int og = gt % TPR;
  if (m >= M_) return;
  const int base = m & ~(N_-1);       // b*N_
  const int P = 2*O;
  const float4 u0 = *(const float4*)&ua[(size_t)m*P + og*4];
  const float4 a0 = *(const float4*)&ua[(size_t)m*P + O + og*4];
  const float srs = rsqrtf(1.f + 1e-5f);
  const float4 gv  = *(const float4*)&g[og*4];
  const float4 bv4 = *(const float4*)&bb[og*4];
  const float sx = gv.x*srs, sy = gv.y*srs, sz = gv.z*srs, sw = gv.w*srs;
  const float cx = a0.x - u0.x, cy = a0.y - u0.y, cz = a0.z - u0.z, cw = a0.w - u0.w;
  float mx = -INFINITY, my = -INFINITY, mz = -INFINITY, mw = -INFINITY;
  const int* id = idx + (size_t)m*KNN;
#pragma unroll
  for (int k=0;k<KNN;k++){
    int j = id[k];
    const float4 uj = *(const float4*)&ua[(size_t)(base + j)*P + og*4];
    float zx = fmaf(sx, uj.x + cx, bv4.x);
    float zy = fmaf(sy, uj.y + cy, bv4.y);
    float zz = fmaf(sz, uj.z + cz, bv4.z);
    float zw = fmaf(sw, uj.w + cw, bv4.w);
    mx = fmaxf(mx, mishf(zx));
    my = fmaxf(my, mishf(zy));
    mz = fmaxf(mz, mishf(zz));
    mw = fmaxf(mw, mishf(zw));
  }
  *(float4*)&Y[(size_t)m*O + og*4] = make_float4(mx,my,mz,mw);
}

// ---------------- final projection: out(B,2,N) = W9 @ h8 ----------------
__global__ __launch_bounds__(256) void k_final(const float* __restrict__ h,
                                               const float* __restrict__ W9,
                                               float* __restrict__ out){
  __shared__ float w[128];
  const int t = threadIdx.x;
  if (t < 128) w[t] = W9[t];
  __syncthreads();
  const int m = blockIdx.x*256 + t;
  if (m >= M_) return;
  const int b = m >> 12, i = m & (N_-1);
  const float* hr = h + (size_t)m*64;
  float s0 = 0.f, s1 = 0.f;
#pragma unroll
  for (int c=0;c<64;c++){ float v = hr[c]; s0 = fmaf(w[c], v, s0); s1 = fmaf(w[64+c], v, s1); }
  out[((size_t)b*2 + 0)*N_ + i] = s0;
  out[((size_t)b*2 + 1)*N_ + i] = s1;
}

extern "C" void kernel_launch(void* const* d_in, const int* in_sizes, int n_in,
                              void* d_out, int out_size, void* d_ws, size_t ws_size,
                              hipStream_t stream)
{
  const float* x  = (const float*)d_in[0];
  const float* W1 = (const float*)d_in[1];
  const float* W2 = (const float*)d_in[2];
  const float* W3 = (const float*)d_in[3];
  const float* W4 = (const float*)d_in[4];
  const float* W5 = (const float*)d_in[5];
  const float* W6 = (const float*)d_in[6];
  const float* W7 = (const float*)d_in[7];
  const float* W8 = (const float*)d_in[8];
  const float* W9 = (const float*)d_in[9];
  const float* g1 = (const float*)d_in[10]; const float* b1 = (const float*)d_in[11];
  const float* g2 = (const float*)d_in[12]; const float* b2 = (const float*)d_in[13];
  const float* g3 = (const float*)d_in[14]; const float* b3 = (const float*)d_in[15];
  const float* g4 = (const float*)d_in[16]; const float* b4 = (const float*)d_in[17];
  const float* g5 = (const float*)d_in[18]; const float* b5 = (const float*)d_in[19];
  const float* g6 = (const float*)d_in[20]; const float* b6 = (const float*)d_in[21];
  const float* g7 = (const float*)d_in[22]; const float* b7 = (const float*)d_in[23];
  const float* g8 = (const float*)d_in[24]; const float* b8 = (const float*)d_in[25];
  float* out = (float*)d_out;

  float* ws  = (float*)d_ws;
  float* xp  = ws;                       // 98304
  float* xx  = xp + 98304;               // 32768
  int*   idx = (int*)(xx + 32768);       // 327680 ints
  float* ua  = (float*)(idx + 327680);   // 8388608 (max M*256)
  float* x1  = ua + 8388608;             // M*64
  float* x2  = x1 + 2097152;             // M*64
  float* x3  = x2 + 2097152;             // M*128
  float* h4  = x3 + 4194304;             // M*128
  float* h5  = h4 + 4194304;             // M*128
  float* h6  = x3;   // alias: x3 dead after h5
  float* h7  = h4;   // alias: h4 dead after h5
  float* h8  = h5;   // alias: h5 dead after h6

  const dim3 blk(256);
  const float* nullf = nullptr;

  // ---- stage 1 (C=3 -> 64) ----
  k_transpose_x<<<dim3(M_/256), blk, 0, stream>>>(x, xp);
  k_xx<3><<<dim3(M_/256), blk, 0, stream>>>(xp, xx);
  k_knn<3><<<dim3(N_/64, B_), blk, 0, stream>>>(xp, xx, idx);
  k_gemm<128><<<dim3(M_/64, 1), blk, 0, stream>>>(xp, 3, nullf, 0,
      W1, 63, 6, 6, 3, nullf, nullf, 0, ua, 128);
  k_edgemax<64><<<dim3(M_*16/256), blk, 0, stream>>>(ua, idx, g1, b1, x1);

  // ---- stage 2 (64 -> 64) ----
  k_xx<64><<<dim3(M_/256), blk, 0, stream>>>(x1, xx);
  k_knn<64><<<dim3(N_/64, B_), blk, 0, stream>>>(x1, xx, idx);
  k_gemm<128><<<dim3(M_/64, 1), blk, 0, stream>>>(x1, 64, nullf, 0,
      W2, 63, 6, 128, 64, nullf, nullf, 0, ua, 128);
  k_edgemax<64><<<dim3(M_*16/256), blk, 0, stream>>>(ua, idx, g2, b2, x2);

  // ---- stage 3 (64 -> 128) ----
  k_xx<64><<<dim3(M_/256), blk, 0, stream>>>(x2, xx);
  k_knn<64><<<dim3(N_/64, B_), blk, 0, stream>>>(x2, xx, idx);
  k_gemm<128><<<dim3(M_/64, 2), blk, 0, stream>>>(x2, 64, nullf, 0,
      W3, 127, 7, 128, 64, nullf, nullf, 0, ua, 256);
  k_edgemax<128><<<dim3(M_*32/256), blk, 0, stream>>>(ua, idx, g3, b3, x3);

  // ---- MLP head ----
  k_gemm<128><<<dim3(M_/64, 1), blk, 0, stream>>>(x3, 128, nullf, 0,
      W4, 127, 7, 128, 0, g4, b4, 1, h4, 128);
  k_gemm<128><<<dim3(M_/64, 1), blk, 0, stream>>>(h4, 128, x3, 128,
      W5, 127, 7, 256, 0, g5, b5, 1, h5, 128);
  k_gemm<64><<<dim3(M_/64, 1), blk, 0, stream>>>(h5, 128, nullf, 0,
      W6, 63, 6, 128, 0, g6, b6, 1, h6, 64);
  k_gemm<64><<<dim3(M_/64, 1), blk, 0, stream>>>(h6, 64, x2, 64,
      W7, 63, 6, 128, 0, g7, b7, 1, h7, 64);
  k_gemm<64><<<dim3(M_/64, 1), blk, 0, stream>>>(h7, 64, x1, 64,
      W8, 63, 6, 128, 0, g8, b8, 1, h8, 64);
  k_final<<<dim3(M_/256), blk, 0, stream>>>(h8, W9, out);
}

// Round 4
// 1896.719 us; speedup vs baseline: 2.5346x; 2.5346x over previous
//
#include <hip/hip_runtime.h>
#include <math.h>
#include <float.h>

#define B_ 8
#define N_ 4096
#define M_ (B_*N_)
#define KNN 10

__device__ __forceinline__ float mishf(float x){
  float sp = (x > 20.f) ? x : __logf(1.f + __expf(x));
  float e2 = __expf(-2.f*sp);
  float th = (1.f - e2) / (1.f + e2);
  return x * th;
}

__device__ __forceinline__ unsigned long long shfl_xor_u64(unsigned long long v, int mask){
  unsigned lo = (unsigned)v, hi = (unsigned)(v >> 32);
  lo = (unsigned)__shfl_xor((int)lo, mask);
  hi = (unsigned)__shfl_xor((int)hi, mask);
  return ((unsigned long long)hi << 32) | lo;
}

// ---------------- transpose x (B,3,N) -> xp (B*N,3) ----------------
__global__ __launch_bounds__(256) void k_transpose_x(const float* __restrict__ x,
                                                     float* __restrict__ xp){
  int n = blockIdx.x*256 + threadIdx.x;
  if (n >= M_) return;
  int b = n >> 12, i = n & (N_-1);
  const float* xb = x + (size_t)b*3*N_;
  float v0 = xb[i], v1 = xb[N_+i], v2 = xb[2*N_+i];
  float* o = xp + (size_t)n*3;
  o[0]=v0; o[1]=v1; o[2]=v2;
}

// ---------------- xx[n] = sum_c X[n,c]^2 ----------------
template<int C>
__global__ __launch_bounds__(256) void k_xx(const float* __restrict__ X,
                                            float* __restrict__ xx){
  int n = blockIdx.x*256 + threadIdx.x;
  if (n >= M_) return;
  const float* r = X + (size_t)n*C;
  float s = 0.f;
#pragma unroll
  for (int c=0;c<C;c++){ float v=r[c]; s = fmaf(v,v,s); }
  xx[n] = s;
}

// ---------------- fused gram + top-10 kNN ----------------
// block: 64 rows x 4096 cols, JT=128 col tiles. 256 thr, thread tile 4 rows x 8 cols.
// selection value inner(i,j) - 0.5*xx_j computed IN the gram via an extra channel:
//   XI channel C = 1.0, XJ channel C = -0.5*xx_j.
// top-k as u64 keys: (monotone_u32(value) << 32) | (4095-j)  -- FULL fp32 precision,
// tie -> smaller j (matches top_k stable order). merge: 16-lane shuffle tournament.
template<int C>
__global__ __launch_bounds__(256,2) void k_knn(const float* __restrict__ X,
                                               const float* __restrict__ xx,
                                               int* __restrict__ idxout){
  constexpr bool BIG = (C % 4 == 0);
  constexpr int LS  = BIG ? (C + 4) : 12;   // row stride: fold channel lives in the pad
  constexpr int NC4 = BIG ? (C/4 + 1) : 1;  // float4 steps incl fold step
  constexpr int JT  = 128;
  __shared__ float XI[64*LS];
  __shared__ float XJ[JT*LS];

  const int t  = threadIdx.x;
  const int b  = blockIdx.y;
  const int i0 = blockIdx.x*64;
  const int tc = t & 15, tr = t >> 4;       // col-group (8 cols), row-group (4 rows)
  const float* Xb  = X  + (size_t)b*N_*C;
  const float* xxb = xx + (size_t)b*N_;

  // ---- stage XI (once) ----
  if constexpr (BIG){
    for (int f = t; f < 64*(C/4); f += 256){
      int r = f >> 4, c4 = f & 15;
      *(float4*)&XI[r*LS + c4*4] = *(const float4*)&Xb[(size_t)(i0+r)*C + c4*4];
    }
    if (t < 64){ XI[t*LS+C]=1.f; XI[t*LS+C+1]=0.f; XI[t*LS+C+2]=0.f; XI[t*LS+C+3]=0.f; }
  } else {
    if (t < 64){
      const float* p = &Xb[(size_t)(i0+t)*C];
      XI[t*LS+0]=p[0]; XI[t*LS+1]=p[1]; XI[t*LS+2]=p[2]; XI[t*LS+3]=1.f;
    }
  }

  unsigned long long keys[4][KNN];
#pragma unroll
  for (int rr=0;rr<4;rr++)
#pragma unroll
    for (int q=0;q<KNN;q++) keys[rr][q]=0ull;

  for (int jt = 0; jt < N_/JT; ++jt){
    const int j0 = jt*JT;
    // ---- stage XJ ----
    if constexpr (BIG){
      for (int f = t; f < JT*(C/4); f += 256){
        int r = f >> 4, c4 = f & 15;
        *(float4*)&XJ[r*LS + c4*4] = *(const float4*)&Xb[(size_t)(j0+r)*C + c4*4];
      }
      if (t < JT){ XJ[t*LS+C] = -0.5f*xxb[j0+t]; XJ[t*LS+C+1]=0.f; XJ[t*LS+C+2]=0.f; XJ[t*LS+C+3]=0.f; }
    } else {
      if (t < JT){
        const float* p = &Xb[(size_t)(j0+t)*C];
        XJ[t*LS+0]=p[0]; XJ[t*LS+1]=p[1]; XJ[t*LS+2]=p[2]; XJ[t*LS+3]=-0.5f*xxb[j0+t];
      }
    }
    __syncthreads();

    // ---- gram: acc[rr][s] = inner(i0+tr*4+rr, j0+tc+16s) - 0.5*xx_j ----
    float acc[4][8];
#pragma unroll
    for (int rr=0;rr<4;rr++)
#pragma unroll
      for (int s=0;s<8;s++) acc[rr][s]=0.f;

#pragma unroll 2
    for (int c4 = 0; c4 < NC4; ++c4){
      float4 xi0 = *(const float4*)&XI[(tr*4+0)*LS + c4*4];
      float4 xi1 = *(const float4*)&XI[(tr*4+1)*LS + c4*4];
      float4 xi2 = *(const float4*)&XI[(tr*4+2)*LS + c4*4];
      float4 xi3 = *(const float4*)&XI[(tr*4+3)*LS + c4*4];
#pragma unroll
      for (int s=0;s<8;s++){
        float4 xj = *(const float4*)&XJ[(tc+16*s)*LS + c4*4];
        float a0=acc[0][s], a1=acc[1][s], a2=acc[2][s], a3=acc[3][s];
        a0=fmaf(xi0.x,xj.x,a0); a1=fmaf(xi1.x,xj.x,a1); a2=fmaf(xi2.x,xj.x,a2); a3=fmaf(xi3.x,xj.x,a3);
        a0=fmaf(xi0.y,xj.y,a0); a1=fmaf(xi1.y,xj.y,a1); a2=fmaf(xi2.y,xj.y,a2); a3=fmaf(xi3.y,xj.y,a3);
        a0=fmaf(xi0.z,xj.z,a0); a1=fmaf(xi1.z,xj.z,a1); a2=fmaf(xi2.z,xj.z,a2); a3=fmaf(xi3.z,xj.z,a3);
        a0=fmaf(xi0.w,xj.w,a0); a1=fmaf(xi1.w,xj.w,a1); a2=fmaf(xi2.w,xj.w,a2); a3=fmaf(xi3.w,xj.w,a3);
        acc[0][s]=a0; acc[1][s]=a1; acc[2][s]=a2; acc[3][s]=a3;
      }
    }

    // ---- selection: pack (full fp32 value, index tie-break) and insert ----
#pragma unroll
    for (int s=0;s<8;s++){
      const unsigned jinv = 4095u - (unsigned)(j0 + tc + 16*s);
#pragma unroll
      for (int rr=0;rr<4;rr++){
        unsigned u  = __float_as_uint(acc[rr][s]);
        unsigned sm = (unsigned)((int)u >> 31);
        unsigned vk = (u ^ (sm | 0x80000000u));
        unsigned long long key = ((unsigned long long)vk << 32) | jinv;
        if (key > keys[rr][KNN-1]){
          unsigned long long ck = key;
#pragma unroll
          for (int q=0;q<KNN;q++){
            unsigned long long hi = ck > keys[rr][q] ? ck : keys[rr][q];
            unsigned long long lo = ck > keys[rr][q] ? keys[rr][q] : ck;
            keys[rr][q] = hi; ck = lo;
          }
        }
      }
    }
    __syncthreads();   // XJ consumed; safe to restage
  }

  // ---- merge: tournament over the 16 lanes (tc) owning each row ----
#pragma unroll
  for (int rr=0;rr<4;rr++){
    int* o = idxout + ((size_t)b*N_ + i0 + tr*4 + rr)*KNN;
    for (int slot=0; slot<KNN; ++slot){
      unsigned long long m = keys[rr][0];
      unsigned long long v1 = shfl_xor_u64(m, 1); m = m > v1 ? m : v1;
      unsigned long long v2 = shfl_xor_u64(m, 2); m = m > v2 ? m : v2;
      unsigned long long v4 = shfl_xor_u64(m, 4); m = m > v4 ? m : v4;
      unsigned long long v8 = shfl_xor_u64(m, 8); m = m > v8 ? m : v8;
      bool won = (keys[rr][0] == m);
#pragma unroll
      for (int q=0;q<KNN-1;q++) keys[rr][q] = won ? keys[rr][q+1] : keys[rr][q];
      keys[rr][KNN-1] = won ? 0ull : keys[rr][KNN-1];
      if (tc == 0) o[slot] = (int)(4095u - ((unsigned)m & 4095u));
    }
  }
}

// ---------------- generic GEMM: Y(M x Pfull) = act(s*(X1@Wa + X2@Wb)+b) ----------
// weight row for output col p: W + (p&hmask)*wstride + (p>>hshift)*hoff, length C
template<int PT>
__global__ __launch_bounds__(256) void k_gemm(
    const float* __restrict__ X1, int C1,
    const float* __restrict__ X2, int C2,
    const float* __restrict__ W, int hmask, int hshift, int wstride, int hoff,
    const float* __restrict__ g, const float* __restrict__ bb, int act,
    float* __restrict__ Y, int Pfull)
{
  constexpr int CPT = PT/16;     // cols per thread
  constexpr int WLS = PT + 4;
  __shared__ float Xt[32*68];    // [kk][r]
  __shared__ float Wt[32*WLS];   // [kk][p]
  const int t  = threadIdx.x;
  const int r0 = blockIdx.x*64;
  const int p0 = blockIdx.y*PT;
  const int cg = t & 15, rg = t >> 4;   // cols cg*CPT.., rows rg*4..
  const int C = C1 + C2;
  const int nkt = (C + 31) >> 5;

  float acc[4][CPT];
#pragma unroll
  for (int a=0;a<4;a++)
#pragma unroll
    for (int c=0;c<CPT;c++) acc[a][c]=0.f;

  for (int kt = 0; kt < nkt; ++kt){
    const int k0 = kt*32;
#pragma unroll
    for (int e = t; e < 64*32; e += 256){
      int kk = e & 31, r = e >> 5;
      int gk = k0 + kk;
      float v = 0.f;
      if (gk < C1) v = X1[(size_t)(r0+r)*C1 + gk];
      else if (gk < C) v = X2[(size_t)(r0+r)*C2 + (gk - C1)];
      Xt[kk*68 + r] = v;
    }
#pragma unroll
    for (int e = t; e < PT*32; e += 256){
      int kk = e & 31, p = e >> 5;
      int gp = p0 + p;
      int wrow = (gp & hmask)*wstride + (gp >> hshift)*hoff;
      int gk = k0 + kk;
      Wt[kk*WLS + p] = (gk < C) ? W[(size_t)wrow + gk] : 0.f;
    }
    __syncthreads();
#pragma unroll
    for (int kk=0;kk<32;kk++){
      float4 xv = *(const float4*)&Xt[kk*68 + rg*4];
      float xr[4] = {xv.x, xv.y, xv.z, xv.w};
      float wv[CPT];
#pragma unroll
      for (int c4=0;c4<CPT/4;c4++){
        float4 w4 = *(const float4*)&Wt[kk*WLS + cg*CPT + c4*4];
        wv[c4*4+0]=w4.x; wv[c4*4+1]=w4.y; wv[c4*4+2]=w4.z; wv[c4*4+3]=w4.w;
      }
#pragma unroll
      for (int rr=0;rr<4;rr++)
#pragma unroll
        for (int cc=0;cc<CPT;cc++)
          acc[rr][cc] = fmaf(xr[rr], wv[cc], acc[rr][cc]);
    }
    __syncthreads();
  }

  const float srs = rsqrtf(1.f + 1e-5f);
  float sv[CPT], bvv[CPT];
#pragma unroll
  for (int cc=0;cc<CPT;cc++){
    int gp = p0 + cg*CPT + cc;
    if (g){ sv[cc] = g[gp]*srs; bvv[cc] = bb[gp]; } else { sv[cc]=1.f; bvv[cc]=0.f; }
  }
#pragma unroll
  for (int rr=0;rr<4;rr++){
    size_t row = r0 + rg*4 + rr;
    float* yr = Y + row*(size_t)Pfull + p0 + cg*CPT;
#pragma unroll
    for (int c4=0;c4<CPT/4;c4++){
      float y0 = sv[c4*4+0]*acc[rr][c4*4+0] + bvv[c4*4+0];
      float y1 = sv[c4*4+1]*acc[rr][c4*4+1] + bvv[c4*4+1];
      float y2 = sv[c4*4+2]*acc[rr][c4*4+2] + bvv[c4*4+2];
      float y3 = sv[c4*4+3]*acc[rr][c4*4+3] + bvv[c4*4+3];
      if (act){ y0=mishf(y0); y1=mishf(y1); y2=mishf(y2); y3=mishf(y3); }
      *(float4*)&yr[c4*4] = make_float4(y0,y1,y2,y3);
    }
  }
}

// ---------------- edge gather + BN + mish + max over k ----------------
// ua layout: row m -> [u_0..u_{O-1}, a_0..a_{O-1}]
template<int O>
__global__ __launch_bounds__(256) void k_edgemax(
    const float* __restrict__ ua, const int* __restrict__ idx,
    const float* __restrict__ g, const float* __restrict__ bb,
    float* __restrict__ Y)
{
  constexpr int TPR = O/4;
  const int gt = blockIdx.x*256 + threadIdx.x;
  const int m  = gt / TPR;
  const int og = gt % TPR;
  if (m >= M_) return;
  const int base = m & ~(N_-1);       // b*N_
  const int P = 2*O;
  const float4 u0 = *(const float4*)&ua[(size_t)m*P + og*4];
  const float4 a0 = *(const float4*)&ua[(size_t)m*P + O + og*4];
  const float srs = rsqrtf(1.f + 1e-5f);
  const float4 gv  = *(const float4*)&g[og*4];
  const float4 bv4 = *(const float4*)&bb[og*4];
  const float sx = gv.x*srs, sy = gv.y*srs, sz = gv.z*srs, sw = gv.w*srs;
  const float cx = a0.x - u0.x, cy = a0.y - u0.y, cz = a0.z - u0.z, cw = a0.w - u0.w;
  float mx = -INFINITY, my = -INFINITY, mz = -INFINITY, mw = -INFINITY;
  const int* id = idx + (size_t)m*KNN;
#pragma unroll
  for (int k=0;k<KNN;k++){
    int j = id[k];
    const float4 uj = *(const float4*)&ua[(size_t)(base + j)*P + og*4];
    float zx = fmaf(sx, uj.x + cx, bv4.x);
    float zy = fmaf(sy, uj.y + cy, bv4.y);
    float zz = fmaf(sz, uj.z + cz, bv4.z);
    float zw = fmaf(sw, uj.w + cw, bv4.w);
    mx = fmaxf(mx, mishf(zx));
    my = fmaxf(my, mishf(zy));
    mz = fmaxf(mz, mishf(zz));
    mw = fmaxf(mw, mishf(zw));
  }
  *(float4*)&Y[(size_t)m*O + og*4] = make_float4(mx,my,mz,mw);
}

// ---------------- final projection: out(B,2,N) = W9 @ h8 ----------------
__global__ __launch_bounds__(256) void k_final(const float* __restrict__ h,
                                               const float* __restrict__ W9,
                                               float* __restrict__ out){
  __shared__ float w[128];
  const int t = threadIdx.x;
  if (t < 128) w[t] = W9[t];
  __syncthreads();
  const int m = blockIdx.x*256 + t;
  if (m >= M_) return;
  const int b = m >> 12, i = m & (N_-1);
  const float* hr = h + (size_t)m*64;
  float s0 = 0.f, s1 = 0.f;
#pragma unroll
  for (int c=0;c<64;c++){ float v = hr[c]; s0 = fmaf(w[c], v, s0); s1 = fmaf(w[64+c], v, s1); }
  out[((size_t)b*2 + 0)*N_ + i] = s0;
  out[((size_t)b*2 + 1)*N_ + i] = s1;
}

extern "C" void kernel_launch(void* const* d_in, const int* in_sizes, int n_in,
                              void* d_out, int out_size, void* d_ws, size_t ws_size,
                              hipStream_t stream)
{
  const float* x  = (const float*)d_in[0];
  const float* W1 = (const float*)d_in[1];
  const float* W2 = (const float*)d_in[2];
  const float* W3 = (const float*)d_in[3];
  const float* W4 = (const float*)d_in[4];
  const float* W5 = (const float*)d_in[5];
  const float* W6 = (const float*)d_in[6];
  const float* W7 = (const float*)d_in[7];
  const float* W8 = (const float*)d_in[8];
  const float* W9 = (const float*)d_in[9];
  const float* g1 = (const float*)d_in[10]; const float* b1 = (const float*)d_in[11];
  const float* g2 = (const float*)d_in[12]; const float* b2 = (const float*)d_in[13];
  const float* g3 = (const float*)d_in[14]; const float* b3 = (const float*)d_in[15];
  const float* g4 = (const float*)d_in[16]; const float* b4 = (const float*)d_in[17];
  const float* g5 = (const float*)d_in[18]; const float* b5 = (const float*)d_in[19];
  const float* g6 = (const float*)d_in[20]; const float* b6 = (const float*)d_in[21];
  const float* g7 = (const float*)d_in[22]; const float* b7 = (const float*)d_in[23];
  const float* g8 = (const float*)d_in[24]; const float* b8 = (const float*)d_in[25];
  float* out = (float*)d_out;

  float* ws  = (float*)d_ws;
  float* xp  = ws;                       // 98304
  float* xx  = xp + 98304;               // 32768
  int*   idx = (int*)(xx + 32768);       // 327680 ints
  float* ua  = (float*)(idx + 327680);   // 8388608 (max M*256)
  float* x1  = ua + 8388608;             // M*64
  float* x2  = x1 + 2097152;             // M*64
  float* x3  = x2 + 2097152;             // M*128
  float* h4  = x3 + 4194304;             // M*128
  float* h5  = h4 + 4194304;             // M*128
  float* h6  = x3;   // alias: x3 dead after h5
  float* h7  = h4;   // alias: h4 dead after h5
  float* h8  = h5;   // alias: h5 dead after h6

  const dim3 blk(256);
  const float* nullf = nullptr;

  // ---- stage 1 (C=3 -> 64) ----
  k_transpose_x<<<dim3(M_/256), blk, 0, stream>>>(x, xp);
  k_xx<3><<<dim3(M_/256), blk, 0, stream>>>(xp, xx);
  k_knn<3><<<dim3(N_/64, B_), blk, 0, stream>>>(xp, xx, idx);
  k_gemm<128><<<dim3(M_/64, 1), blk, 0, stream>>>(xp, 3, nullf, 0,
      W1, 63, 6, 6, 3, nullf, nullf, 0, ua, 128);
  k_edgemax<64><<<dim3(M_*16/256), blk, 0, stream>>>(ua, idx, g1, b1, x1);

  // ---- stage 2 (64 -> 64) ----
  k_xx<64><<<dim3(M_/256), blk, 0, stream>>>(x1, xx);
  k_knn<64><<<dim3(N_/64, B_), blk, 0, stream>>>(x1, xx, idx);
  k_gemm<128><<<dim3(M_/64, 1), blk, 0, stream>>>(x1, 64, nullf, 0,
      W2, 63, 6, 128, 64, nullf, nullf, 0, ua, 128);
  k_edgemax<64><<<dim3(M_*16/256), blk, 0, stream>>>(ua, idx, g2, b2, x2);

  // ---- stage 3 (64 -> 128) ----
  k_xx<64><<<dim3(M_/256), blk, 0, stream>>>(x2, xx);
  k_knn<64><<<dim3(N_/64, B_), blk, 0, stream>>>(x2, xx, idx);
  k_gemm<128><<<dim3(M_/64, 2), blk, 0, stream>>>(x2, 64, nullf, 0,
      W3, 127, 7, 128, 64, nullf, nullf, 0, ua, 256);
  k_edgemax<128><<<dim3(M_*32/256), blk, 0, stream>>>(ua, idx, g3, b3, x3);

  // ---- MLP head ----
  k_gemm<128><<<dim3(M_/64, 1), blk, 0, stream>>>(x3, 128, nullf, 0,
      W4, 127, 7, 128, 0, g4, b4, 1, h4, 128);
  k_gemm<128><<<dim3(M_/64, 1), blk, 0, stream>>>(h4, 128, x3, 128,
      W5, 127, 7, 256, 0, g5, b5, 1, h5, 128);
  k_gemm<64><<<dim3(M_/64, 1), blk, 0, stream>>>(h5, 128, nullf, 0,
      W6, 63, 6, 128, 0, g6, b6, 1, h6, 64);
  k_gemm<64><<<dim3(M_/64, 1), blk, 0, stream>>>(h6, 64, x2, 64,
      W7, 63, 6, 128, 0, g7, b7, 1, h7, 64);
  k_gemm<64><<<dim3(M_/64, 1), blk, 0, stream>>>(h7, 64, x1, 64,
      W8, 63, 6, 128, 0, g8, b8, 1, h8, 64);
  k_final<<<dim3(M_/256), blk, 0, stream>>>(h8, W9, out);
}